// Round 7
// baseline (399.690 us; speedup 1.0000x reference)
//
#include <hip/hip_runtime.h>

typedef __attribute__((ext_vector_type(8))) short bf16x8;
typedef __attribute__((ext_vector_type(4))) float f32x4;

__device__ __forceinline__ unsigned short f2bf(float f) {
  unsigned int u = __builtin_bit_cast(unsigned int, f);
  u += 0x7fffu + ((u >> 16) & 1u);   // round-to-nearest-even
  return (unsigned short)(u >> 16);
}

// v_cvt_pk_bf16_f32: D[15:0]=bf16(lo), D[31:16]=bf16(hi), RNE (T12 recipe)
__device__ __forceinline__ unsigned int cvt_pk_bf16(float lo, float hi) {
  unsigned int r;
  asm("v_cvt_pk_bf16_f32 %0, %1, %2" : "=v"(r) : "v"(lo), "v"(hi));
  return r;
}

typedef const __attribute__((address_space(1))) unsigned int* as1_u32p;
typedef __attribute__((address_space(3))) unsigned int* as3_u32p;
__device__ __forceinline__ void glds16(const void* g, void* l) {
  __builtin_amdgcn_global_load_lds((as1_u32p)g, (as3_u32p)l, 16, 0, 0);
}

// ---------------------------------------------------------------------------
// K0: bulk fp32 -> bf16 convert (8 elems/thread)
// ---------------------------------------------------------------------------
__global__ __launch_bounds__(256) void cvt_kernel(const float* __restrict__ X,
                                                  unsigned short* __restrict__ Y) {
  const long long i = ((long long)blockIdx.x * 256 + threadIdx.x) * 8;
  float4 a = *reinterpret_cast<const float4*>(X + i);
  float4 b = *reinterpret_cast<const float4*>(X + i + 4);
  bf16x8 t;
  t[0] = (short)f2bf(a.x); t[1] = (short)f2bf(a.y);
  t[2] = (short)f2bf(a.z); t[3] = (short)f2bf(a.w);
  t[4] = (short)f2bf(b.x); t[5] = (short)f2bf(b.y);
  t[6] = (short)f2bf(b.z); t[7] = (short)f2bf(b.w);
  *reinterpret_cast<bf16x8*>(Y + i) = t;
}

// ---------------------------------------------------------------------------
// K0t: fp32 [R][C] -> bf16 [C][R] transpose (32x32 tiles)
// ---------------------------------------------------------------------------
__global__ __launch_bounds__(256) void transpose_bf16_kernel(
    const float* __restrict__ S, unsigned short* __restrict__ D, int R, int C) {
  __shared__ float T[32][33];
  const int bx = blockIdx.x * 32;  // col tile
  const int by = blockIdx.y * 32;  // row tile
  const int tx = threadIdx.x & 31, ty = threadIdx.x >> 5;
#pragma unroll
  for (int k = 0; k < 4; ++k)
    T[ty + 8 * k][tx] = S[(size_t)(by + ty + 8 * k) * C + bx + tx];
  __syncthreads();
#pragma unroll
  for (int k = 0; k < 4; ++k)
    D[(size_t)(bx + ty + 8 * k) * R + by + tx] = f2bf(T[tx][ty + 8 * k]);
}

// ---------------------------------------------------------------------------
// K0m: mask bit-pack to u32 words via ballot.
// Mb[g>>5] bit (g&31) = (mask[g] != 0), g = (s*256+row)*256 + k.  512 KiB.
// ---------------------------------------------------------------------------
__global__ __launch_bounds__(256) void pack_mask_kernel(const int* __restrict__ mask,
                                                        unsigned int* __restrict__ Mb) {
  const int g = blockIdx.x * 256 + threadIdx.x;
  const unsigned long long bal = __ballot(mask[g] != 0);
  const int lane = threadIdx.x & 63;
  if ((lane & 31) == 0)
    Mb[g >> 5] = (unsigned int)(bal >> (lane & 32));
}

// ---------------------------------------------------------------------------
// K1/K3: bf16 GEMM  C[M][N] = A[M][K] * Bt[N][K]^T (+bias), fp32 accum.
// m97 structure: 128x128 tile, BK=32, glds width-16 staging, single buffer,
// 2 barriers/K-step (proven fastest configuration for this shape).
// ---------------------------------------------------------------------------
template <bool C_F32>
__global__ __launch_bounds__(256) void gemm_bt(
    const unsigned short* __restrict__ A,   // [M][K] bf16
    const unsigned short* __restrict__ Bt,  // [N][K] bf16
    void* __restrict__ Cv,
    const float* __restrict__ bias,         // [N] fp32 (C_F32 only)
    int M, int N, int K)
{
  __shared__ __align__(16) unsigned short As[128 * 32];  // unpadded (GLDS layout)
  __shared__ __align__(16) unsigned short Bs[128 * 32];

  const int tid  = threadIdx.x;
  const int bm   = blockIdx.x * 128;
  const int bn   = blockIdx.y * 128;
  const int lane = tid & 63;
  const int wave = tid >> 6;
  const int wr   = (wave >> 1) * 64;
  const int wc   = (wave & 1) * 64;
  const int l15  = lane & 15;
  const int quad = lane >> 4;

  f32x4 acc[4][4];
#pragma unroll
  for (int r = 0; r < 4; ++r)
#pragma unroll
    for (int c = 0; c < 4; ++c) {
      f32x4 z = {0.f, 0.f, 0.f, 0.f};
      acc[r][c] = z;
    }

  // per-lane global srcs; wave-uniform LDS dests (dest = base + lane*16B)
  const unsigned short* gA0 = A  + (size_t)(bm + wave * 16 + (lane >> 2)) * K + (lane & 3) * 8;
  const unsigned short* gA1 = gA0 + (size_t)64 * K;
  const unsigned short* gB0 = Bt + (size_t)(bn + wave * 16 + (lane >> 2)) * K + (lane & 3) * 8;
  const unsigned short* gB1 = gB0 + (size_t)64 * K;
  unsigned short* lA0 = As + wave * 512;
  unsigned short* lA1 = As + 2048 + wave * 512;
  unsigned short* lB0 = Bs + wave * 512;
  unsigned short* lB1 = Bs + 2048 + wave * 512;

  for (int kk = 0; kk < K; kk += 32) {
    glds16(gA0 + kk, lA0);
    glds16(gA1 + kk, lA1);
    glds16(gB0 + kk, lB0);
    glds16(gB1 + kk, lB1);
    __syncthreads();   // drains vmcnt before barrier (compiler-enforced)

    bf16x8 af[4], bf[4];
#pragma unroll
    for (int i = 0; i < 4; ++i) {
      af[i] = *reinterpret_cast<const bf16x8*>(&As[(wr + i * 16 + l15) * 32 + quad * 8]);
      bf[i] = *reinterpret_cast<const bf16x8*>(&Bs[(wc + i * 16 + l15) * 32 + quad * 8]);
    }
#pragma unroll
    for (int rt = 0; rt < 4; ++rt)
#pragma unroll
      for (int ct = 0; ct < 4; ++ct)
        acc[rt][ct] = __builtin_amdgcn_mfma_f32_16x16x32_bf16(af[rt], bf[ct], acc[rt][ct], 0, 0, 0);
    __syncthreads();
  }

  // epilogue: D[row=quad*4+i][col=l15] per 16x16 tile (proven layout)
#pragma unroll
  for (int rt = 0; rt < 4; ++rt)
#pragma unroll
    for (int ct = 0; ct < 4; ++ct)
#pragma unroll
      for (int i = 0; i < 4; ++i) {
        const int row = bm + wr + rt * 16 + quad * 4 + i;
        const int col = bn + wc + ct * 16 + l15;
        const float v = acc[rt][ct][i];
        if constexpr (C_F32) {
          ((float*)Cv)[(size_t)row * N + col] = v + bias[col];
        } else {
          ((unsigned short*)Cv)[(size_t)row * N + col] = f2bf(v);
        }
      }
}

// ---------------------------------------------------------------------------
// K2: masked softmax attention — swapped QK^T + permuted-k PV, V^T in LDS.
//
// Changes vs R6 (spill fix):
//  - __launch_bounds__(256, 3): R6's (256,4) forced VGPR=64 -> massive
//    scratch spill (FETCH +223MB, WRITE +115MB).  Cap ~168 fits the ~150
//    live set; 3 blocks/CU (vs R3's 2).
//  - bv[2][8] V B-frags hoisted out of the qb loop (built once from Vt).
//  - tree-shaped max/sum reductions (f32x4 elementwise chains, depth 63->~18).
//  - deferred per-OUTPUT-row 1/sum via __shfl(sum, quad*4+i) (proven R6).
// ---------------------------------------------------------------------------
#define SCALE_F 0.17677669529663689f

__global__ __launch_bounds__(256, 3) void attn_kernel(
    const unsigned short* __restrict__ QKV,   // [t][768] bf16: Q|K|V
    const unsigned int* __restrict__ Mb,      // [64*256][8] u32 bit-packed mask
    unsigned short* __restrict__ Aout)        // [65536][256] bf16
{
  __shared__ __align__(16) unsigned short Ks[256 * 32];  // XOR-swizzled, 16384 B
  __shared__ __align__(16) unsigned short Vt[32 * 264];  // V^T, stride 264, 16896 B

  const int blk  = blockIdx.x;   // 0..2047
  const int h    = blk & 7;
  const int sb   = blk >> 3;
  const int s    = sb >> 2;
  const int t0   = sb << 8;
  const int tid  = threadIdx.x;
  const int lane = tid & 63;
  const int wave = tid >> 6;
  const int l15  = lane & 15;
  const int quad = lane >> 4;

  // ---- hoisted Q frags for all 4 qb (B-operand: Q[qbase+l15][quad*8+j]) ----
  bf16x8 qf[4];
#pragma unroll
  for (int qb = 0; qb < 4; ++qb)
    qf[qb] = *reinterpret_cast<const bf16x8*>(
        QKV + (size_t)(t0 + wave * 64 + qb * 16 + l15) * 768 + h * 32 + quad * 8);

  // ---- stage K (swizzled row-major) and V (transposed, d-major) ----
  {
    const unsigned short* kp = QKV + (size_t)(t0 + tid) * 768 + 256 + h * 32;
    const unsigned short* vp = kp + 256;
    const int sw = (tid >> 1) & 3;              // K row-granule swizzle
    unsigned short* kd = Ks + tid * 32;
#pragma unroll
    for (int g = 0; g < 4; ++g)
      *reinterpret_cast<uint4*>(kd + ((g ^ sw) << 3)) = *reinterpret_cast<const uint4*>(kp + g * 8);
    uint4 v0 = *reinterpret_cast<const uint4*>(vp);
    uint4 v1 = *reinterpret_cast<const uint4*>(vp + 8);
    uint4 v2 = *reinterpret_cast<const uint4*>(vp + 16);
    uint4 v3 = *reinterpret_cast<const uint4*>(vp + 24);
    unsigned int dw[16] = {v0.x, v0.y, v0.z, v0.w, v1.x, v1.y, v1.z, v1.w,
                           v2.x, v2.y, v2.z, v2.w, v3.x, v3.y, v3.z, v3.w};
#pragma unroll
    for (int w = 0; w < 16; ++w) {
      Vt[(2 * w) * 264 + tid]     = (unsigned short)dw[w];
      Vt[(2 * w + 1) * 264 + tid] = (unsigned short)(dw[w] >> 16);
    }
  }
  __syncthreads();

  const int swr = (l15 >> 1) & 3;   // K-read granule swizzle (row = ct*16+l15)
  const int q4  = quad * 4;

  // ---- V B-frags with permuted k-slots, built ONCE (k = c*32 + pi(quad,j)) ----
  bf16x8 bv[2][8];
#pragma unroll
  for (int dt = 0; dt < 2; ++dt) {
    const unsigned short* vr = Vt + (dt * 16 + l15) * 264;
#pragma unroll
    for (int c = 0; c < 8; ++c) {
      uint2 a = *reinterpret_cast<const uint2*>(vr + c * 32 + q4);
      uint2 b = *reinterpret_cast<const uint2*>(vr + c * 32 + 16 + q4);
      uint4 u = {a.x, a.y, b.x, b.y};
      bv[dt][c] = __builtin_bit_cast(bf16x8, u);
    }
  }

  for (int qb = 0; qb < 4; ++qb) {
    const int qbase = wave * 64 + qb * 16;

    // mask bits for this lane's q-row, pre-shifted by quad*4: bit for
    // sim[ct][i] is msk[ct>>1] bit ((ct&1)*16 + i)  (compile-time pos).
    unsigned int msk[8];
    {
      const unsigned int* mrow = Mb + (((size_t)s * 256 + qbase + l15) << 3);
      uint4 m0 = *reinterpret_cast<const uint4*>(mrow);
      uint4 m1 = *reinterpret_cast<const uint4*>(mrow + 4);
      msk[0] = m0.x >> q4; msk[1] = m0.y >> q4; msk[2] = m0.z >> q4; msk[3] = m0.w >> q4;
      msk[4] = m1.x >> q4; msk[5] = m1.y >> q4; msk[6] = m1.z >> q4; msk[7] = m1.w >> q4;
    }

    // swapped QK^T: sim[ct][i] = S_raw[q=qbase+l15][k=ct*16+quad*4+i]
    f32x4 sim[16];
#pragma unroll
    for (int ct = 0; ct < 16; ++ct) {
      bf16x8 kf = *reinterpret_cast<const bf16x8*>(
          &Ks[(ct * 16 + l15) * 32 + ((quad ^ swr) << 3)]);
      f32x4 z = {0.f, 0.f, 0.f, 0.f};
      sim[ct] = __builtin_amdgcn_mfma_f32_16x16x32_bf16(kf, qf[qb], z, 0, 0, 0);
    }

    // row max over RAW scores, tree-shaped: 4 elementwise chains then combine
    f32x4 m4 = sim[0];
#pragma unroll
    for (int ct = 1; ct < 16; ++ct)
#pragma unroll
      for (int i = 0; i < 4; ++i)
        m4[i] = fmaxf(m4[i], sim[ct][i]);
    float mx = fmaxf(fmaxf(m4[0], m4[1]), fmaxf(m4[2], m4[3]));
    mx = fmaxf(mx, __shfl_xor(mx, 16, 64));
    mx = fmaxf(mx, __shfl_xor(mx, 32, 64));
    const float nms = -mx * SCALE_F;

    // e = exp((sim - mx)*SCALE); zero masked via sbfe(0/-1)&; 4 partial sums
    f32x4 s4 = {0.f, 0.f, 0.f, 0.f};
#pragma unroll
    for (int ct = 0; ct < 16; ++ct)
#pragma unroll
      for (int i = 0; i < 4; ++i) {
        float e = __expf(fmaf(sim[ct][i], SCALE_F, nms));
        const int keep = __builtin_amdgcn_sbfe((int)msk[ct >> 1], (ct & 1) * 16 + i, 1);
        e = __builtin_bit_cast(float, __builtin_bit_cast(int, e) & keep);
        sim[ct][i] = e;
        s4[i] += e;
      }
    float sum = (s4[0] + s4[1]) + (s4[2] + s4[3]);
    sum += __shfl_xor(sum, 16, 64);
    sum += __shfl_xor(sum, 32, 64);

    // output-row sums: row r's sum lives in lanes with l15==r (all quads);
    // lane's outputs are rows quad*4+i -> broadcast from lane q4+i (<16).
    float rl[4];
#pragma unroll
    for (int i = 0; i < 4; ++i)
      rl[i] = 1.0f / __shfl(sum, q4 + i, 64);

    // PV with UNNORMALIZED P (A-frag = cvt_pk pairs of own sim; pi-permuted)
    f32x4 o0 = {0.f, 0.f, 0.f, 0.f};
    f32x4 o1 = {0.f, 0.f, 0.f, 0.f};
#pragma unroll
    for (int c = 0; c < 8; ++c) {
      uint4 u;
      u.x = cvt_pk_bf16(sim[2 * c][0],     sim[2 * c][1]);
      u.y = cvt_pk_bf16(sim[2 * c][2],     sim[2 * c][3]);
      u.z = cvt_pk_bf16(sim[2 * c + 1][0], sim[2 * c + 1][1]);
      u.w = cvt_pk_bf16(sim[2 * c + 1][2], sim[2 * c + 1][3]);
      bf16x8 pf = __builtin_bit_cast(bf16x8, u);
      o0 = __builtin_amdgcn_mfma_f32_16x16x32_bf16(pf, bv[0][c], o0, 0, 0, 0);
      o1 = __builtin_amdgcn_mfma_f32_16x16x32_bf16(pf, bv[1][c], o1, 0, 0, 0);
    }

    // D: lane holds O[q=qbase+quad*4+i][d]; normalize by that ROW's 1/sum
#pragma unroll
    for (int i = 0; i < 4; ++i) {
      const size_t row = (size_t)t0 + qbase + quad * 4 + i;
      Aout[row * 256 + h * 32 + l15]      = f2bf(o0[i] * rl[i]);
      Aout[row * 256 + h * 32 + 16 + l15] = f2bf(o1[i] * rl[i]);
    }
  }
}

// ---------------------------------------------------------------------------
// Memory plan:
//   ws[0, 96MiB)        QKV  (live K1->attn); WoutT transposed into ws[0]
//                             AFTER attn (QKV dead) for K3.
//   ws[96MiB, 128MiB)   Xbf  (live cvt->K1), then Amid aliases it (attn->K3).
//   d_out[0, 384KB)     WqkvT scratch (live ->K1; K1 only READS d_out).
//   d_out[32MiB, 32.5MiB) Mbits bit-packed mask (live pack->attn).
//   K3 overwrites all of d_out at the end.
// ---------------------------------------------------------------------------
extern "C" void kernel_launch(void* const* d_in, const int* in_sizes, int n_in,
                              void* d_out, int out_size, void* d_ws, size_t ws_size,
                              hipStream_t stream) {
  const float* X    = (const float*)d_in[0];  // [65536][256] fp32
  const int*   mask = (const int*)d_in[1];    // [64][256][256] int32
  const float* Wqkv = (const float*)d_in[2];  // [256][768] fp32
  const float* Wout = (const float*)d_in[3];  // [256][256] fp32
  const float* bout = (const float*)d_in[4];  // [256] fp32
  float*       outp = (float*)d_out;          // [65536][256] fp32

  unsigned short* QKV   = (unsigned short*)d_ws;       // 96 MiB
  unsigned short* Xbf   = QKV + (size_t)65536 * 768;   // 32 MiB
  unsigned short* Amid  = Xbf;                         // alias: Xbf dead after K1
  unsigned short* WoutT = QKV;                         // alias: QKV dead after attn
  unsigned short* WqkvT = (unsigned short*)d_out;      // d_out scratch, dead before K3
  unsigned int*   Mbits = (unsigned int*)((char*)d_out + ((size_t)32 << 20));

  dim3 blk(256);
  cvt_kernel<<<dim3(8192), blk, 0, stream>>>(X, Xbf);
  transpose_bf16_kernel<<<dim3(24, 8), blk, 0, stream>>>(Wqkv, WqkvT, 256, 768);
  pack_mask_kernel<<<dim3(16384), blk, 0, stream>>>(mask, Mbits);

  gemm_bt<false><<<dim3(512, 6), blk, 0, stream>>>(Xbf, WqkvT, (void*)QKV, nullptr, 65536, 768, 256);
  attn_kernel<<<dim3(2048), blk, 0, stream>>>(QKV, Mbits, Amid);

  transpose_bf16_kernel<<<dim3(8, 8), blk, 0, stream>>>(Wout, WoutT, 256, 256);
  gemm_bt<true><<<dim3(512, 2), blk, 0, stream>>>(Amid, WoutT, (void*)outp, bout, 65536, 256, 256);
}

// Round 8
// 313.593 us; speedup vs baseline: 1.2745x; 1.2745x over previous
//
#include <hip/hip_runtime.h>

typedef __attribute__((ext_vector_type(8))) short bf16x8;
typedef __attribute__((ext_vector_type(4))) float f32x4;

__device__ __forceinline__ unsigned short f2bf(float f) {
  unsigned int u = __builtin_bit_cast(unsigned int, f);
  u += 0x7fffu + ((u >> 16) & 1u);   // round-to-nearest-even
  return (unsigned short)(u >> 16);
}

// v_cvt_pk_bf16_f32: D[15:0]=bf16(lo), D[31:16]=bf16(hi), RNE (T12 recipe)
__device__ __forceinline__ unsigned int cvt_pk_bf16(float lo, float hi) {
  unsigned int r;
  asm("v_cvt_pk_bf16_f32 %0, %1, %2" : "=v"(r) : "v"(lo), "v"(hi));
  return r;
}

typedef const __attribute__((address_space(1))) unsigned int* as1_u32p;
typedef __attribute__((address_space(3))) unsigned int* as3_u32p;
__device__ __forceinline__ void glds16(const void* g, void* l) {
  __builtin_amdgcn_global_load_lds((as1_u32p)g, (as3_u32p)l, 16, 0, 0);
}

// ---------------------------------------------------------------------------
// K0: bulk fp32 -> bf16 convert (8 elems/thread)
// ---------------------------------------------------------------------------
__global__ __launch_bounds__(256) void cvt_kernel(const float* __restrict__ X,
                                                  unsigned short* __restrict__ Y) {
  const long long i = ((long long)blockIdx.x * 256 + threadIdx.x) * 8;
  float4 a = *reinterpret_cast<const float4*>(X + i);
  float4 b = *reinterpret_cast<const float4*>(X + i + 4);
  bf16x8 t;
  t[0] = (short)f2bf(a.x); t[1] = (short)f2bf(a.y);
  t[2] = (short)f2bf(a.z); t[3] = (short)f2bf(a.w);
  t[4] = (short)f2bf(b.x); t[5] = (short)f2bf(b.y);
  t[6] = (short)f2bf(b.z); t[7] = (short)f2bf(b.w);
  *reinterpret_cast<bf16x8*>(Y + i) = t;
}

// ---------------------------------------------------------------------------
// K0t: fp32 [R][C] -> bf16 [C][R] transpose (32x32 tiles)
// ---------------------------------------------------------------------------
__global__ __launch_bounds__(256) void transpose_bf16_kernel(
    const float* __restrict__ S, unsigned short* __restrict__ D, int R, int C) {
  __shared__ float T[32][33];
  const int bx = blockIdx.x * 32;  // col tile
  const int by = blockIdx.y * 32;  // row tile
  const int tx = threadIdx.x & 31, ty = threadIdx.x >> 5;
#pragma unroll
  for (int k = 0; k < 4; ++k)
    T[ty + 8 * k][tx] = S[(size_t)(by + ty + 8 * k) * C + bx + tx];
  __syncthreads();
#pragma unroll
  for (int k = 0; k < 4; ++k)
    D[(size_t)(bx + ty + 8 * k) * R + by + tx] = f2bf(T[tx][ty + 8 * k]);
}

// ---------------------------------------------------------------------------
// K0m: mask bit-pack to u32 words via ballot.
// Mb[g>>5] bit (g&31) = (mask[g] != 0), g = (s*256+row)*256 + k.  512 KiB.
// ---------------------------------------------------------------------------
__global__ __launch_bounds__(256) void pack_mask_kernel(const int* __restrict__ mask,
                                                        unsigned int* __restrict__ Mb) {
  const int g = blockIdx.x * 256 + threadIdx.x;
  const unsigned long long bal = __ballot(mask[g] != 0);
  const int lane = threadIdx.x & 63;
  if ((lane & 31) == 0)
    Mb[g >> 5] = (unsigned int)(bal >> (lane & 32));
}

// ---------------------------------------------------------------------------
// K1/K3: bf16 GEMM  C[M][N] = A[M][K] * Bt[N][K]^T (+bias), fp32 accum.
// m97 structure: 128x128 tile, BK=32, glds width-16 staging, single buffer,
// 2 barriers/K-step (proven fastest configuration for this shape).
// ---------------------------------------------------------------------------
template <bool C_F32>
__global__ __launch_bounds__(256) void gemm_bt(
    const unsigned short* __restrict__ A,   // [M][K] bf16
    const unsigned short* __restrict__ Bt,  // [N][K] bf16
    void* __restrict__ Cv,
    const float* __restrict__ bias,         // [N] fp32 (C_F32 only)
    int M, int N, int K)
{
  __shared__ __align__(16) unsigned short As[128 * 32];  // unpadded (GLDS layout)
  __shared__ __align__(16) unsigned short Bs[128 * 32];

  const int tid  = threadIdx.x;
  const int bm   = blockIdx.x * 128;
  const int bn   = blockIdx.y * 128;
  const int lane = tid & 63;
  const int wave = tid >> 6;
  const int wr   = (wave >> 1) * 64;
  const int wc   = (wave & 1) * 64;
  const int l15  = lane & 15;
  const int quad = lane >> 4;

  f32x4 acc[4][4];
#pragma unroll
  for (int r = 0; r < 4; ++r)
#pragma unroll
    for (int c = 0; c < 4; ++c) {
      f32x4 z = {0.f, 0.f, 0.f, 0.f};
      acc[r][c] = z;
    }

  // per-lane global srcs; wave-uniform LDS dests (dest = base + lane*16B)
  const unsigned short* gA0 = A  + (size_t)(bm + wave * 16 + (lane >> 2)) * K + (lane & 3) * 8;
  const unsigned short* gA1 = gA0 + (size_t)64 * K;
  const unsigned short* gB0 = Bt + (size_t)(bn + wave * 16 + (lane >> 2)) * K + (lane & 3) * 8;
  const unsigned short* gB1 = gB0 + (size_t)64 * K;
  unsigned short* lA0 = As + wave * 512;
  unsigned short* lA1 = As + 2048 + wave * 512;
  unsigned short* lB0 = Bs + wave * 512;
  unsigned short* lB1 = Bs + 2048 + wave * 512;

  for (int kk = 0; kk < K; kk += 32) {
    glds16(gA0 + kk, lA0);
    glds16(gA1 + kk, lA1);
    glds16(gB0 + kk, lB0);
    glds16(gB1 + kk, lB1);
    __syncthreads();   // drains vmcnt before barrier (compiler-enforced)

    bf16x8 af[4], bf[4];
#pragma unroll
    for (int i = 0; i < 4; ++i) {
      af[i] = *reinterpret_cast<const bf16x8*>(&As[(wr + i * 16 + l15) * 32 + quad * 8]);
      bf[i] = *reinterpret_cast<const bf16x8*>(&Bs[(wc + i * 16 + l15) * 32 + quad * 8]);
    }
#pragma unroll
    for (int rt = 0; rt < 4; ++rt)
#pragma unroll
      for (int ct = 0; ct < 4; ++ct)
        acc[rt][ct] = __builtin_amdgcn_mfma_f32_16x16x32_bf16(af[rt], bf[ct], acc[rt][ct], 0, 0, 0);
    __syncthreads();
  }

  // epilogue: D[row=quad*4+i][col=l15] per 16x16 tile (proven layout)
#pragma unroll
  for (int rt = 0; rt < 4; ++rt)
#pragma unroll
    for (int ct = 0; ct < 4; ++ct)
#pragma unroll
      for (int i = 0; i < 4; ++i) {
        const int row = bm + wr + rt * 16 + quad * 4 + i;
        const int col = bn + wc + ct * 16 + l15;
        const float v = acc[rt][ct][i];
        if constexpr (C_F32) {
          ((float*)Cv)[(size_t)row * N + col] = v + bias[col];
        } else {
          ((unsigned short*)Cv)[(size_t)row * N + col] = f2bf(v);
        }
      }
}

// ---------------------------------------------------------------------------
// K2: masked softmax attention — swapped QK^T + permuted-k PV, V^T in LDS.
//
// Changes vs R7:
//  - NO __launch_bounds__ min-waves: both (256,4) and (256,3) made the
//    allocator overshoot (VGPR 64/84) and spill 300+MB of scratch.  Pressure
//    is reduced STRUCTURALLY instead: V frags are NOT hoisted (bv[2][8] was
//    64 VGPRs) — read per-c from Vt inside the PV loop (hidden under MFMA).
//  - row-sum via MFMA against a ones B-frag: os[i] = masked row sum in the
//    OUTPUT-row layout (os[i] belongs to row quad*4+i, same as o0/o1[i]).
//    Deletes the sum tree + 2 shfl_xor + 4 shfl broadcasts per qb.
//  - exp2 with folded constant (fmaf+v_exp instead of fmaf+mul+v_exp).
//  - keeps: raw-score tree-max, sbfe+and masking, mask/Q hoists, Ks swizzle.
// ---------------------------------------------------------------------------
#define EXP2_SCALE 0.2550348660629988f   // (1/sqrt(32)) * log2(e)

__global__ __launch_bounds__(256) void attn_kernel(
    const unsigned short* __restrict__ QKV,   // [t][768] bf16: Q|K|V
    const unsigned int* __restrict__ Mb,      // [64*256][8] u32 bit-packed mask
    unsigned short* __restrict__ Aout)        // [65536][256] bf16
{
  __shared__ __align__(16) unsigned short Ks[256 * 32];  // XOR-swizzled, 16384 B
  __shared__ __align__(16) unsigned short Vt[32 * 264];  // V^T, stride 264, 16896 B

  const int blk  = blockIdx.x;   // 0..2047
  const int h    = blk & 7;
  const int sb   = blk >> 3;
  const int s    = sb >> 2;
  const int t0   = sb << 8;
  const int tid  = threadIdx.x;
  const int lane = tid & 63;
  const int wave = tid >> 6;
  const int l15  = lane & 15;
  const int quad = lane >> 4;

  // ---- hoisted Q frags for all 4 qb (B-operand: Q[qbase+l15][quad*8+j]) ----
  bf16x8 qf[4];
#pragma unroll
  for (int qb = 0; qb < 4; ++qb)
    qf[qb] = *reinterpret_cast<const bf16x8*>(
        QKV + (size_t)(t0 + wave * 64 + qb * 16 + l15) * 768 + h * 32 + quad * 8);

  // ---- stage K (swizzled row-major) and V (transposed, d-major) ----
  {
    const unsigned short* kp = QKV + (size_t)(t0 + tid) * 768 + 256 + h * 32;
    const unsigned short* vp = kp + 256;
    const int sw = (tid >> 1) & 3;              // K row-granule swizzle
    unsigned short* kd = Ks + tid * 32;
#pragma unroll
    for (int g = 0; g < 4; ++g)
      *reinterpret_cast<uint4*>(kd + ((g ^ sw) << 3)) = *reinterpret_cast<const uint4*>(kp + g * 8);
    uint4 v0 = *reinterpret_cast<const uint4*>(vp);
    uint4 v1 = *reinterpret_cast<const uint4*>(vp + 8);
    uint4 v2 = *reinterpret_cast<const uint4*>(vp + 16);
    uint4 v3 = *reinterpret_cast<const uint4*>(vp + 24);
    unsigned int dw[16] = {v0.x, v0.y, v0.z, v0.w, v1.x, v1.y, v1.z, v1.w,
                           v2.x, v2.y, v2.z, v2.w, v3.x, v3.y, v3.z, v3.w};
#pragma unroll
    for (int w = 0; w < 16; ++w) {
      Vt[(2 * w) * 264 + tid]     = (unsigned short)dw[w];
      Vt[(2 * w + 1) * 264 + tid] = (unsigned short)(dw[w] >> 16);
    }
  }
  __syncthreads();

  const int swr = (l15 >> 1) & 3;   // K-read granule swizzle (row = ct*16+l15)
  const int q4  = quad * 4;
  const unsigned short* vr0 = Vt + l15 * 264;         // dt=0 row (d = l15)
  const unsigned short* vr1 = Vt + (16 + l15) * 264;  // dt=1 row (d = 16+l15)

  // ones B-frag for the row-sum MFMA (bf16 1.0 = 0x3F80)
  const uint4 onesu = {0x3F803F80u, 0x3F803F80u, 0x3F803F80u, 0x3F803F80u};
  const bf16x8 ones = __builtin_bit_cast(bf16x8, onesu);

  for (int qb = 0; qb < 4; ++qb) {
    const int qbase = wave * 64 + qb * 16;

    // mask bits for this lane's q-row, pre-shifted by quad*4: bit for
    // sim[ct][i] is msk[ct>>1] bit ((ct&1)*16 + i)  (compile-time pos).
    unsigned int msk[8];
    {
      const unsigned int* mrow = Mb + (((size_t)s * 256 + qbase + l15) << 3);
      uint4 m0 = *reinterpret_cast<const uint4*>(mrow);
      uint4 m1 = *reinterpret_cast<const uint4*>(mrow + 4);
      msk[0] = m0.x >> q4; msk[1] = m0.y >> q4; msk[2] = m0.z >> q4; msk[3] = m0.w >> q4;
      msk[4] = m1.x >> q4; msk[5] = m1.y >> q4; msk[6] = m1.z >> q4; msk[7] = m1.w >> q4;
    }

    // swapped QK^T: sim[ct][i] = S_raw[q=qbase+l15][k=ct*16+quad*4+i]
    f32x4 sim[16];
#pragma unroll
    for (int ct = 0; ct < 16; ++ct) {
      bf16x8 kf = *reinterpret_cast<const bf16x8*>(
          &Ks[(ct * 16 + l15) * 32 + ((quad ^ swr) << 3)]);
      f32x4 z = {0.f, 0.f, 0.f, 0.f};
      sim[ct] = __builtin_amdgcn_mfma_f32_16x16x32_bf16(kf, qf[qb], z, 0, 0, 0);
    }

    // row max over RAW scores, tree-shaped (common exp factor cancels)
    f32x4 m4 = sim[0];
#pragma unroll
    for (int ct = 1; ct < 16; ++ct)
#pragma unroll
      for (int i = 0; i < 4; ++i)
        m4[i] = fmaxf(m4[i], sim[ct][i]);
    float mx = fmaxf(fmaxf(m4[0], m4[1]), fmaxf(m4[2], m4[3]));
    mx = fmaxf(mx, __shfl_xor(mx, 16, 64));
    mx = fmaxf(mx, __shfl_xor(mx, 32, 64));
    const float nms2 = -mx * EXP2_SCALE;

    // e = exp2(fmaf(sim, C, nms2)); zero masked via sbfe(0/-1) &
#pragma unroll
    for (int ct = 0; ct < 16; ++ct)
#pragma unroll
      for (int i = 0; i < 4; ++i) {
        float e = __builtin_amdgcn_exp2f(fmaf(sim[ct][i], EXP2_SCALE, nms2));
        const int keep = __builtin_amdgcn_sbfe((int)msk[ct >> 1], (ct & 1) * 16 + i, 1);
        sim[ct][i] = __builtin_bit_cast(float, __builtin_bit_cast(int, e) & keep);
      }

    // PV with UNNORMALIZED P; V frags read per-c from Vt (not hoisted);
    // os = P . ones gives the masked row-sum in the OUTPUT-row layout.
    f32x4 o0 = {0.f, 0.f, 0.f, 0.f};
    f32x4 o1 = {0.f, 0.f, 0.f, 0.f};
    f32x4 os = {0.f, 0.f, 0.f, 0.f};
#pragma unroll
    for (int c = 0; c < 8; ++c) {
      uint4 u;
      u.x = cvt_pk_bf16(sim[2 * c][0],     sim[2 * c][1]);
      u.y = cvt_pk_bf16(sim[2 * c][2],     sim[2 * c][3]);
      u.z = cvt_pk_bf16(sim[2 * c + 1][0], sim[2 * c + 1][1]);
      u.w = cvt_pk_bf16(sim[2 * c + 1][2], sim[2 * c + 1][3]);
      bf16x8 pf = __builtin_bit_cast(bf16x8, u);
      uint2 a0 = *reinterpret_cast<const uint2*>(vr0 + c * 32 + q4);
      uint2 b0 = *reinterpret_cast<const uint2*>(vr0 + c * 32 + 16 + q4);
      uint2 a1 = *reinterpret_cast<const uint2*>(vr1 + c * 32 + q4);
      uint2 b1 = *reinterpret_cast<const uint2*>(vr1 + c * 32 + 16 + q4);
      uint4 u0v = {a0.x, a0.y, b0.x, b0.y};
      uint4 u1v = {a1.x, a1.y, b1.x, b1.y};
      o0 = __builtin_amdgcn_mfma_f32_16x16x32_bf16(pf, __builtin_bit_cast(bf16x8, u0v), o0, 0, 0, 0);
      o1 = __builtin_amdgcn_mfma_f32_16x16x32_bf16(pf, __builtin_bit_cast(bf16x8, u1v), o1, 0, 0, 0);
      os = __builtin_amdgcn_mfma_f32_16x16x32_bf16(pf, ones, os, 0, 0, 0);
    }

    // D: lane holds O[q=qbase+quad*4+i][d] AND its row-sum os[i]
#pragma unroll
    for (int i = 0; i < 4; ++i) {
      const float rl = 1.0f / os[i];
      const size_t row = (size_t)t0 + qbase + quad * 4 + i;
      Aout[row * 256 + h * 32 + l15]      = f2bf(o0[i] * rl);
      Aout[row * 256 + h * 32 + 16 + l15] = f2bf(o1[i] * rl);
    }
  }
}

// ---------------------------------------------------------------------------
// Memory plan:
//   ws[0, 96MiB)        QKV  (live K1->attn); WoutT transposed into ws[0]
//                             AFTER attn (QKV dead) for K3.
//   ws[96MiB, 128MiB)   Xbf  (live cvt->K1), then Amid aliases it (attn->K3).
//   d_out[0, 384KB)     WqkvT scratch (live ->K1; K1 only READS d_out).
//   d_out[32MiB, 32.5MiB) Mbits bit-packed mask (live pack->attn).
//   K3 overwrites all of d_out at the end.
// ---------------------------------------------------------------------------
extern "C" void kernel_launch(void* const* d_in, const int* in_sizes, int n_in,
                              void* d_out, int out_size, void* d_ws, size_t ws_size,
                              hipStream_t stream) {
  const float* X    = (const float*)d_in[0];  // [65536][256] fp32
  const int*   mask = (const int*)d_in[1];    // [64][256][256] int32
  const float* Wqkv = (const float*)d_in[2];  // [256][768] fp32
  const float* Wout = (const float*)d_in[3];  // [256][256] fp32
  const float* bout = (const float*)d_in[4];  // [256] fp32
  float*       outp = (float*)d_out;          // [65536][256] fp32

  unsigned short* QKV   = (unsigned short*)d_ws;       // 96 MiB
  unsigned short* Xbf   = QKV + (size_t)65536 * 768;   // 32 MiB
  unsigned short* Amid  = Xbf;                         // alias: Xbf dead after K1
  unsigned short* WoutT = QKV;                         // alias: QKV dead after attn
  unsigned short* WqkvT = (unsigned short*)d_out;      // d_out scratch, dead before K3
  unsigned int*   Mbits = (unsigned int*)((char*)d_out + ((size_t)32 << 20));

  dim3 blk(256);
  cvt_kernel<<<dim3(8192), blk, 0, stream>>>(X, Xbf);
  transpose_bf16_kernel<<<dim3(24, 8), blk, 0, stream>>>(Wqkv, WqkvT, 256, 768);
  pack_mask_kernel<<<dim3(16384), blk, 0, stream>>>(mask, Mbits);

  gemm_bt<false><<<dim3(512, 6), blk, 0, stream>>>(Xbf, WqkvT, (void*)QKV, nullptr, 65536, 768, 256);
  attn_kernel<<<dim3(2048), blk, 0, stream>>>(QKV, Mbits, Amid);

  transpose_bf16_kernel<<<dim3(8, 8), blk, 0, stream>>>(Wout, WoutT, 256, 256);
  gemm_bt<true><<<dim3(512, 2), blk, 0, stream>>>(Amid, WoutT, (void*)outp, bout, 65536, 256, 256);
}